// Round 7
// baseline (296.966 us; speedup 1.0000x reference)
//
#include <hip/hip_runtime.h>
#include <math.h>

#define BSZ 2
#define SEQ 2048
#define NH 16
#define DH 64
#define DM 1024
#define HD 1024

typedef _Float16 h16;
typedef _Float16 half8 __attribute__((ext_vector_type(8)));
typedef _Float16 half4 __attribute__((ext_vector_type(4)));
typedef float f32x4 __attribute__((ext_vector_type(4)));
typedef unsigned int u32;
typedef unsigned int u32x2v __attribute__((ext_vector_type(2)));
typedef unsigned int u32x4v __attribute__((ext_vector_type(4)));

__device__ __forceinline__ f32x4 mfma16(half8 a, half8 b, f32x4 c) {
    return __builtin_amdgcn_mfma_f32_16x16x32_f16(a, b, c, 0, 0, 0);
}

// Async global->LDS, 16B per lane. HW writes lane i to ldsbase + i*16.
__device__ __forceinline__ void async_copy16(h16* lds, const h16* g) {
    __builtin_amdgcn_global_load_lds(
        (const __attribute__((address_space(1))) unsigned int*)g,
        (__attribute__((address_space(3))) unsigned int*)lds, 16, 0, 0);
}

// XOR-swizzled chunk offset (halfs) for unpadded 64-half rows (8 chunks).
// 128 B rows -> 2-way max bank aliasing (free). The BK=32 QSWZ variant was
// an 8-way conflict (4.75M conflict cycles, R5/R6) -- do not reuse.
#define SWZ(cb, r) ((((cb) ^ ((r) & 7)) * 8))

// Obuf: [128][64] f32, 16B-chunk XOR swizzle (addr in dwords, c multiple of 4).
#define OBA(r, c) ((r) * 64 + ((((c) >> 2) ^ ((r) & 15)) << 2))

#define EXP2(x) __builtin_amdgcn_exp2f(x)

// Pack two f32 -> one u32 of two f16 (lo = a, hi = b), single v_cvt_pkrtz.
__device__ __forceinline__ u32 pack2(float a, float b) {
    auto p = __builtin_amdgcn_cvt_pkrtz(a, b);
    return __builtin_bit_cast(u32, p);
}

// Swap lane-bit5 (lanes +-32) with the a/b register bit.
__device__ __forceinline__ void pl32swap(u32& a, u32& b) {
#if __has_builtin(__builtin_amdgcn_permlane32_swap)
    u32x2v r = __builtin_amdgcn_permlane32_swap(a, b, false, false);
    a = r.x; b = r.y;
#else
    u32 sa = __builtin_amdgcn_ds_swizzle(a, 0x801F);
    u32 sb = __builtin_amdgcn_ds_swizzle(b, 0x801F);
    bool hi = (threadIdx.x & 32) != 0;
    u32 na = hi ? sb : a;
    u32 nb = hi ? b : sa;
    a = na; b = nb;
#endif
}

// Swap lane-bit4 (lanes +-16) with the a/b register bit.
__device__ __forceinline__ void pl16swap(u32& a, u32& b) {
#if __has_builtin(__builtin_amdgcn_permlane16_swap)
    u32x2v r = __builtin_amdgcn_permlane16_swap(a, b, false, false);
    a = r.x; b = r.y;
#else
    u32 sa = __builtin_amdgcn_ds_swizzle(a, 0x401F);
    u32 sb = __builtin_amdgcn_ds_swizzle(b, 0x401F);
    bool hi = (threadIdx.x & 16) != 0;
    u32 na = hi ? sb : a;
    u32 nb = hi ? b : sa;
    a = na; b = nb;
#endif
}

// ---------------------------------------------------------------------------
// Prep (merged): z<4 -> transpose W[k][n] fp32 to WT[n][k] f16;
//                z==4 -> cvt x fp32 -> f16.
// ---------------------------------------------------------------------------
__global__ __launch_bounds__(256) void prep_kernel(
    const float* __restrict__ x, const float* __restrict__ wq,
    const float* __restrict__ wk, const float* __restrict__ wv,
    const float* __restrict__ wo,
    h16* __restrict__ x16, h16* __restrict__ wt)
{
    const int z = blockIdx.z;
    const int t = threadIdx.x;
    if (z == 4) {
        int flat = blockIdx.y * 16 + blockIdx.x;   // 0..255
#pragma unroll
        for (int i = 0; i < 8; ++i) {
            int idx = flat * 16384 + i * 2048 + t * 8;
            float4 a = *(const float4*)&x[idx];
            float4 b = *(const float4*)&x[idx + 4];
            half8 o;
            o[0] = (h16)a.x; o[1] = (h16)a.y; o[2] = (h16)a.z; o[3] = (h16)a.w;
            o[4] = (h16)b.x; o[5] = (h16)b.y; o[6] = (h16)b.z; o[7] = (h16)b.w;
            *(half8*)&x16[idx] = o;
        }
        return;
    }
    const float* w = (z == 0) ? wq : (z == 1) ? wk : (z == 2) ? wv : wo;
    h16* ot = wt + (size_t)z * DM * DM;
    __shared__ float tile[64][68];
    const int k0 = blockIdx.y * 64, n0 = blockIdx.x * 64;
    const int r = t >> 2, c4 = (t & 3) * 16;
#pragma unroll
    for (int i = 0; i < 16; i += 4) {
        float4 v = *(const float4*)&w[(size_t)(k0 + r) * DM + n0 + c4 + i];
        tile[r][c4 + i + 0] = v.x; tile[r][c4 + i + 1] = v.y;
        tile[r][c4 + i + 2] = v.z; tile[r][c4 + i + 3] = v.w;
    }
    __syncthreads();
#pragma unroll
    for (int g = 0; g < 2; ++g) {
        half8 hh;
#pragma unroll
        for (int j = 0; j < 8; ++j)
            hh[j] = (h16)tile[c4 + g * 8 + j][r];
        *(half8*)&ot[(size_t)(n0 + r) * DM + k0 + c4 + g * 8] = hh;
    }
}

// ---------------------------------------------------------------------------
// Kernel 1: QKV projection + RoPE via MFMA, C^T orientation.
// R13 = exact R2 revert: BK=64, SWZ (2-way free), 64 KB dbuf, one exact
// vmcnt(0)+barrier per K-step, prefetch k+64 in flight under step k's MFMAs,
// XCD swizzle. (BK=32 QSWZ variants were 8-way bank-conflicted: 4.75M
// conflict cycles -> 47-52 us. This layout measured ~43-46.)
// z=0: Q (rope+scale); z=1: K (rope); z=2: V -> [B,H,D,S].
// ---------------------------------------------------------------------------
__global__ __launch_bounds__(512, 4) void qkv_kernel(
    const h16* __restrict__ x16, const h16* __restrict__ wt,
    const float* __restrict__ fcos, const float* __restrict__ fsin,
    h16* __restrict__ Q16, h16* __restrict__ K16, h16* __restrict__ VT16)
{
    // XCD-aware swizzle: 768 blocks, id%8 = XCD -> contiguous chunk of 96.
    const int id  = (blockIdx.z * 32 + blockIdx.y) * 8 + blockIdx.x;
    const int swz = (id & 7) * 96 + (id >> 3);
    const int z   = swz >> 8;
    const int m0  = ((swz >> 3) & 31) * 128;   // s-rows
    const int n0  = (swz & 7) * 128;           // features

    const h16* __restrict__ bw = wt + (size_t)z * DM * DM;

    __shared__ h16 smem[32768];   // 64 KB: 2 x (As 8192 + Bs 8192)
    h16* Vt = smem;               // epilogue alias (17408 halfs < 32768)

    const int t  = threadIdx.x;
    const int w  = t >> 6, ln = t & 63;
    const int L  = ln & 15, U = ln >> 4;
    const int wm = (w & 3) * 32;       // s-subtile
    const int wn = (w >> 2) * 64;      // feature-subtile

    const int sr  = ln >> 3;
    const int scb = (ln & 7) ^ sr;

    f32x4 acc[2][4];
#pragma unroll
    for (int i = 0; i < 2; ++i)
#pragma unroll
        for (int j = 0; j < 4; ++j) acc[i][j] = (f32x4)0.0f;

    // prologue: stage k0=0 into buf0
#pragma unroll
    for (int c = 0; c < 2; ++c) {
        int rb = w * 16 + c * 8;
        async_copy16(&smem[rb * 64],        &x16[(size_t)(m0 + rb + sr) * DM + scb * 8]);
        async_copy16(&smem[8192 + rb * 64], &bw [(size_t)(n0 + rb + sr) * DM + scb * 8]);
    }

    for (int k0 = 0; k0 < DM; k0 += 64) {
        const int buf = (k0 >> 6) & 1;
        h16* As = smem + buf * 16384;
        h16* Bs = As + 8192;

        // only this step's 4 staging loads are outstanding -> vmcnt(0) exact
        __builtin_amdgcn_sched_barrier(0);
        asm volatile("s_waitcnt vmcnt(0)" ::: "memory");
        __builtin_amdgcn_s_barrier();
        __builtin_amdgcn_sched_barrier(0);

        // prefetch k0+64 into other buffer (its readers retired before the
        // barrier above); in flight under this step's MFMAs.
        if (k0 + 64 < DM) {
            h16* An = smem + (buf ^ 1) * 16384;
#pragma unroll
            for (int c = 0; c < 2; ++c) {
                int rb = w * 16 + c * 8;
                async_copy16(&An[rb * 64],
                             &x16[(size_t)(m0 + rb + sr) * DM + k0 + 64 + scb * 8]);
                async_copy16(&An[8192 + rb * 64],
                             &bw [(size_t)(n0 + rb + sr) * DM + k0 + 64 + scb * 8]);
            }
        }

        __builtin_amdgcn_s_setprio(1);
#pragma unroll
        for (int ks = 0; ks < 2; ++ks) {
            half8 af[2], bf[4];
#pragma unroll
            for (int mt = 0; mt < 2; ++mt)
                af[mt] = *(const half8*)&As[(wm + mt * 16 + L) * 64 + SWZ(ks * 4 + U, L)];
#pragma unroll
            for (int nt = 0; nt < 4; ++nt)
                bf[nt] = *(const half8*)&Bs[(wn + nt * 16 + L) * 64 + SWZ(ks * 4 + U, L)];
            // C^T: A=weights (m=feature), B=x (n=s-row)
#pragma unroll
            for (int mt = 0; mt < 2; ++mt)
#pragma unroll
                for (int nt = 0; nt < 4; ++nt)
                    acc[mt][nt] = mfma16(bf[nt], af[mt], acc[mt][nt]);
        }
        __builtin_amdgcn_s_setprio(0);
    }

    const int b = m0 >> 11;
    const int sbase = m0 & 2047;

    // acc[mt][nt][r]: feature = wn+nt*16+U*4+r, s_local = wm+mt*16+L
    if (z < 2) {
        const float sc = (z == 0) ? 0.125f * 1.44269504088896f : 1.0f;
#pragma unroll
        for (int mt = 0; mt < 2; ++mt) {
            int s = sbase + wm + mt * 16 + L;
            const float* ct = &fcos[s * 32];
            const float* st = &fsin[s * 32];
#pragma unroll
            for (int nt = 0; nt < 4; ++nt) {
                int nl = n0 + wn + nt * 16 + U * 4;   // multiple of 4
                int d = nl & 63, h = nl >> 6;
                int pd = d >> 1;
                float cv0 = ct[pd], sv0 = st[pd];
                float cv1 = ct[pd + 1], sv1 = st[pd + 1];
                float v0 = acc[mt][nt][0], v1 = acc[mt][nt][1];
                float v2 = acc[mt][nt][2], v3 = acc[mt][nt][3];
                float o0 = (v0 * cv0 - v1 * sv0) * sc;
                float o1 = (v0 * sv0 + v1 * cv0) * sc;
                float o2 = (v2 * cv1 - v3 * sv1) * sc;
                float o3 = (v2 * sv1 + v3 * cv1) * sc;
                size_t addr = ((size_t)(b * NH + h) * SEQ + s) * DH + d;
                half4 kk;
                kk[0] = (h16)o0; kk[1] = (h16)o1; kk[2] = (h16)o2; kk[3] = (h16)o3;
                if (z == 0) *(half4*)&Q16[addr] = kk;
                else        *(half4*)&K16[addr] = kk;
            }
        }
    } else {
        __syncthreads();  // all frag reads done before Vt reuse
#pragma unroll
        for (int mt = 0; mt < 2; ++mt)
#pragma unroll
            for (int nt = 0; nt < 4; ++nt)
#pragma unroll
                for (int r = 0; r < 4; ++r) {
                    int nloc = wn + nt * 16 + U * 4 + r;
                    int sloc = wm + mt * 16 + L;
                    Vt[nloc * 136 + sloc] = (h16)acc[mt][nt][r];
                }
        __syncthreads();
#pragma unroll
        for (int i = 0; i < 4; ++i) {
            int c = i * 512 + t;     // 0..2047
            int dl = c >> 4;         // 0..127
            int s8 = (c & 15) * 8;
            half8 vv = *(const half8*)&Vt[dl * 136 + s8];
            int n = n0 + dl;
            int d = n & 63, h = n >> 6;
            *(half8*)&VT16[((size_t)(b * NH + h) * DH + d) * SEQ + sbase + s8] = vv;
        }
    }
}

// ---------------------------------------------------------------------------
// Kernel 2: flash attention, paired-wave split-K, NO-MAX softmax.
// R13: 48 KB LDS -> 3 blocks/CU (24 waves, was 2 blocks/16 waves). Ks
// single-buffered with the R8-proven 2-barrier schedule; VTs double-buffered;
// in-register P redistribution (permlane) + cvt_pkrtz kept from R10/R11.
// Per iter: [vmcnt(0)+bar] -> issue V[j+1] -> QK^T (reads Ks) ->
// [lgkm(0)+bar] -> issue K[j+1] over Ks -> exp/permlane -> PV (VTs[j&1]).
// ---------------------------------------------------------------------------
__global__ __launch_bounds__(512, 6) void attn_kernel(
    const h16* __restrict__ Q16, const h16* __restrict__ K16,
    const h16* __restrict__ VT16, h16* __restrict__ A16)
{
    __shared__ h16 smem[24576];        // 48 KB exactly
    // Ks: smem[0..8191] ([128][64] swizzled)
    // VTs dbuf: smem+8192 / smem+16384 ([64][128] swizzled each)
    float* lbuf = (float*)smem;            // epilogue alias (Ks region, 1 KB)
    float* Obuf = (float*)(smem + 8192);   // epilogue alias (VTs0+VTs1, 32 KB)

    const int t = threadIdx.x, w = t >> 6, ln = t & 63;
    const int L = ln & 15, U = ln >> 4;
    const int pair = w >> 1, half = w & 1;
    const int qw = pair * 32, kh = half * 64;

    // XCD swizzle: 512 blocks, chunk 64 per XCD -> 4 heads per XCD.
    const int id  = blockIdx.y * 16 + blockIdx.x;
    const int swz = (id & 7) * 64 + (id >> 3);
    const int q0  = (swz & 15) * 128;
    const int bh  = swz >> 4;
    const size_t base = (size_t)bh * SEQ * DH;

    half8 qf[2][2];
#pragma unroll
    for (int qb = 0; qb < 2; ++qb)
#pragma unroll
        for (int ks = 0; ks < 2; ++ks)
            qf[qb][ks] = *(const half8*)&Q16[base + (size_t)(q0 + qw + qb * 16 + L) * DH + ks * 32 + U * 8];

    half8 one8;
#pragma unroll
    for (int i = 0; i < 8; ++i) one8[i] = (h16)1.0f;

    f32x4 O[4][2];
    f32x4 lsum[2];
#pragma unroll
    for (int dt = 0; dt < 4; ++dt)
#pragma unroll
        for (int qb = 0; qb < 2; ++qb) O[dt][qb] = (f32x4)0.0f;
    lsum[0] = (f32x4)0.0f;
    lsum[1] = (f32x4)0.0f;

    const int sr  = ln >> 3;
    const int scb = (ln & 7) ^ sr;

    // ---- prologue: issue K[0] -> Ks, V[0] -> VTs0 ----
#pragma unroll
    for (int c = 0; c < 2; ++c) {
        int rbk = c * 64 + w * 8;
        async_copy16(&smem[rbk * 64], &K16[base + (size_t)(rbk + sr) * DH + scb * 8]);
    }
#pragma unroll
    for (int c = 0; c < 2; ++c) {
        int rv = (w * 2 + c) * 4;
        int c16 = (ln & 15) ^ ((rv + U) & 15);
        async_copy16(&smem[8192 + rv * 128], &VT16[base + (size_t)(rv + U) * SEQ + c16 * 8]);
    }

    for (int j0 = 0; j0 < SEQ; j0 += 128) {
        const int buf = (j0 >> 7) & 1;
        h16* VTcur = smem + 8192 + buf * 8192;

        // Outstanding: K[j] (2) + V[j] (2) only -> vmcnt(0) exact.
        __builtin_amdgcn_sched_barrier(0);
        asm volatile("s_waitcnt vmcnt(0)" ::: "memory");
        __builtin_amdgcn_s_barrier();
        __builtin_amdgcn_sched_barrier(0);

        // prefetch V[j+1] into the other VTs buffer (its iter j-1 readers
        // retired before the barrier above).
        if (j0 + 128 < SEQ) {
            h16* Vnxt = smem + 8192 + (buf ^ 1) * 8192;
#pragma unroll
            for (int c = 0; c < 2; ++c) {
                int rv = (w * 2 + c) * 4;
                int c16 = (ln & 15) ^ ((rv + U) & 15);
                async_copy16(&Vnxt[rv * 128],
                             &VT16[base + (size_t)(rv + U) * SEQ + (j0 + 128) + c16 * 8]);
            }
        }

        // S^T = K Q^T on this wave's k-half (reads Ks)
        f32x4 S[4][2];
        __builtin_amdgcn_s_setprio(1);
#pragma unroll
        for (int nt = 0; nt < 4; ++nt) {
            S[nt][0] = (f32x4)0.0f;
            S[nt][1] = (f32x4)0.0f;
#pragma unroll
            for (int ks = 0; ks < 2; ++ks) {
                half8 kf = *(const half8*)&smem[(kh + nt * 16 + L) * 64 + SWZ(ks * 4 + U, L)];
                S[nt][0] = mfma16(kf, qf[0][ks], S[nt][0]);
                S[nt][1] = mfma16(kf, qf[1][ks], S[nt][1]);
            }
        }
        __builtin_amdgcn_s_setprio(0);

        // all Ks ds_reads retired chip-wide before K[j+1] overwrites Ks.
        __builtin_amdgcn_sched_barrier(0);
        asm volatile("s_waitcnt lgkmcnt(0)" ::: "memory");
        __builtin_amdgcn_sched_barrier(0);
        __builtin_amdgcn_s_barrier();

        // issue K[j+1] over Ks; in flight through exp/PV and next QK wait.
        if (j0 + 128 < SEQ) {
#pragma unroll
            for (int c = 0; c < 2; ++c) {
                int rbk = c * 64 + w * 8;
                async_copy16(&smem[rbk * 64],
                             &K16[base + (size_t)(j0 + 128 + rbk + sr) * DH + scb * 8]);
            }
        }

        // no-max softmax p = exp2(S), redistribute C-layout -> B-layout
        // entirely in registers (permlane32/16_swap; R10 derivation).
        half8 pf[2][2];
#pragma unroll
        for (int qb = 0; qb < 2; ++qb) {
            u32 X[2][2][2];   // [k5][bit=k3][p=k1]
#pragma unroll
            for (int k5 = 0; k5 < 2; ++k5)
#pragma unroll
                for (int p = 0; p < 2; ++p) {
                    u32 a = pack2(EXP2(S[k5 * 2 + 0][qb][2 * p]),
                                  EXP2(S[k5 * 2 + 0][qb][2 * p + 1]));
                    u32 b = pack2(EXP2(S[k5 * 2 + 1][qb][2 * p]),
                                  EXP2(S[k5 * 2 + 1][qb][2 * p + 1]));
                    pl32swap(a, b);
                    X[k5][0][p] = a; X[k5][1][p] = b;
                }
#pragma unroll
            for (int k5 = 0; k5 < 2; ++k5) {
                u32x4v uv;
#pragma unroll
                for (int p = 0; p < 2; ++p) {
                    u32 a = X[k5][0][p], b = X[k5][1][p];
                    pl16swap(a, b);
                    uv[p]     = a;   // (k2=0, k1=p)
                    uv[2 + p] = b;   // (k2=1, k1=p)
                }
                pf[qb][k5] = __builtin_bit_cast(half8, uv);
            }
        }

        // O^T += V^T P ; l += ones^T P (via MFMA), reads VTs[j&1]
        __builtin_amdgcn_s_setprio(1);
#pragma unroll
        for (int dt = 0; dt < 4; ++dt)
#pragma unroll
            for (int ks2 = 0; ks2 < 2; ++ks2) {
                half8 vf = *(const half8*)&VTcur[(dt * 16 + L) * 128 + ((half * 8 + ks2 * 4 + U) ^ L) * 8];
                O[dt][0] = mfma16(vf, pf[0][ks2], O[dt][0]);
                O[dt][1] = mfma16(vf, pf[1][ks2], O[dt][1]);
            }
#pragma unroll
        for (int ks2 = 0; ks2 < 2; ++ks2) {
            lsum[0] = mfma16(one8, pf[0][ks2], lsum[0]);
            lsum[1] = mfma16(one8, pf[1][ks2], lsum[1]);
        }
        __builtin_amdgcn_s_setprio(0);
    }

    // ---- cross-half combine (plain sums) ----
    // lbuf aliases Ks (all Ks reads retired at last mid-iter lgkm+barrier; no
    // K[16] issued). Obuf aliases VTs0+VTs1; writes happen after the first
    // __syncthreads (all PV reads drained), disjoint from lbuf.
    if (U == 0) {
        lbuf[w * 32 + L]      = lsum[0][0];
        lbuf[w * 32 + 16 + L] = lsum[1][0];
    }
    __syncthreads();
    const int pw = w ^ 1;
    float l_tot[2];
    l_tot[0] = lsum[0][0] + lbuf[pw * 32 + L];
    l_tot[1] = lsum[1][0] + lbuf[pw * 32 + 16 + L];

    if (half) {
#pragma unroll
        for (int qb = 0; qb < 2; ++qb)
#pragma unroll
            for (int dt = 0; dt < 4; ++dt)
                *(f32x4*)&Obuf[OBA(qw + qb * 16 + L, dt * 16 + U * 4)] = O[dt][qb];
    }
    __syncthreads();
    if (!half) {
        const int b = bh >> 4, hh = bh & 15;
#pragma unroll
        for (int qb = 0; qb < 2; ++qb) {
            float inv = 1.0f / l_tot[qb];
            int s = q0 + qw + qb * 16 + L;
#pragma unroll
            for (int dt = 0; dt < 4; ++dt) {
                f32x4 op = *(const f32x4*)&Obuf[OBA(qw + qb * 16 + L, dt * 16 + U * 4)];
                half4 o4;
#pragma unroll
                for (int r = 0; r < 4; ++r)
                    o4[r] = (h16)((O[dt][qb][r] + op[r]) * inv);
                *(half4*)&A16[(size_t)(b * SEQ + s) * HD + hh * DH + dt * 16 + U * 4] = o4;
            }
        }
    }
}

// ---------------------------------------------------------------------------
// Kernel 3: output projection, 128x64 tiles, 512 threads = 8 waves,
// wave-tile 16x64, BK=64. Triple-buffered depth-2 prefetch (72 KB ->
// 2 blocks/CU, grid = exactly 2/CU). vmcnt(3): 3 loads/thread/step.
// ---------------------------------------------------------------------------
__global__ __launch_bounds__(512, 4) void oproj_kernel(
    const h16* __restrict__ A16, const h16* __restrict__ bw,
    float* __restrict__ out)
{
    __shared__ h16 smem[36864];   // 72 KB: 3 x (As 8192 + Bs 4096)

    // XCD swizzle: 512 blocks, chunk 64 per XCD.
    const int id  = blockIdx.y * 16 + blockIdx.x;
    const int swz = (id & 7) * 64 + (id >> 3);
    const int n0  = (swz & 15) * 64;
    const int m0  = (swz >> 4) * 128;

    const int t  = threadIdx.x;
    const int w  = t >> 6, ln = t & 63;
    const int L  = ln & 15, U = ln >> 4;

    const int sr  = ln >> 3;
    const int scb = (ln & 7) ^ sr;

    f32x4 acc[4];
#pragma unroll
    for (int j = 0; j < 4; ++j) acc[j] = (f32x4)0.0f;

    // per-thread: 3 loads per step (2 A chunks + 1 B chunk)
    auto stage = [&](int buf, int kk) {
        h16* dst = smem + buf * 12288;
#pragma unroll
        for (int c = 0; c < 2; ++c) {
            int rb = w * 16 + c * 8;
            async_copy16(&dst[rb * 64], &A16[(size_t)(m0 + rb + sr) * DM + kk + scb * 8]);
        }
        async_copy16(&dst[8192 + (w * 8) * 64], &bw[(size_t)(n0 + w * 8 + sr) * DM + kk + scb * 8]);
    };

    // prologue: issue steps 0 and 1
    stage(0, 0);
    stage(1, 64);

    int step = 0;
    for (int k0 = 0; k0 < DM; k0 += 64, ++step) {
        const int buf = step - (step / 3) * 3;   // step % 3
        h16* As = smem + buf * 12288;
        h16* Bs = As + 8192;

        // outstanding: step k (3) + step k+1 (3) = 6 -> vmcnt(3) keeps k+1's
        // loads in flight across the barrier. Last step: vmcnt(0).
        __builtin_amdgcn_sched_barrier(0);
        if (k0 + 64 < DM) asm volatile("s_waitcnt vmcnt(3)" ::: "memory");
        else              asm volatile("s_waitcnt vmcnt(0)" ::: "memory");
        __builtin_amdgcn_s_barrier();
        __builtin_amdgcn_sched_barrier(0);

        if (k0 + 128 < DM) {
            int nb = step + 2;
            stage(nb - (nb / 3) * 3, k0 + 128);
        }

        __builtin_amdgcn_s_setprio(1);
#pragma unroll
        for (int ks = 0; ks < 2; ++ks) {
            half8 af, bf[4];
            af = *(const half8*)&As[(w * 16 + L) * 64 + SWZ(ks * 4 + U, L)];
#pragma unroll
            for (int nt = 0; nt < 4; ++nt)
                bf[nt] = *(const half8*)&Bs[(nt * 16 + L) * 64 + SWZ(ks * 4 + U, L)];
#pragma unroll
            for (int nt = 0; nt < 4; ++nt)
                acc[nt] = mfma16(af, bf[nt], acc[nt]);
        }
        __builtin_amdgcn_s_setprio(0);
    }

#pragma unroll
    for (int nt = 0; nt < 4; ++nt)
#pragma unroll
        for (int r = 0; r < 4; ++r) {
            int row = m0 + w * 16 + U * 4 + r;
            int col = n0 + nt * 16 + L;
            out[(size_t)row * DM + col] = acc[nt][r];
        }
}

extern "C" void kernel_launch(void* const* d_in, const int* in_sizes, int n_in,
                              void* d_out, int out_size, void* d_ws, size_t ws_size,
                              hipStream_t stream)
{
    const float* x    = (const float*)d_in[0];
    const float* fcos = (const float*)d_in[1];
    const float* fsin = (const float*)d_in[2];
    const float* wq   = (const float*)d_in[3];
    const float* wk   = (const float*)d_in[4];
    const float* wv   = (const float*)d_in[5];
    const float* wo   = (const float*)d_in[6];
    float* out = (float*)d_out;

    const size_t M4 = (size_t)4 * 1024 * 1024;
    h16* x16  = (h16*)d_ws;        // 4M halfs
    h16* wt   = x16 + M4;          // 4M (4 matrices, [n][k])
    h16* Q16  = wt + M4;           // 4M
    h16* K16  = Q16 + M4;          // 4M
    h16* VT16 = K16 + M4;          // 4M ([B,H,D,S])
    h16* A16  = VT16 + M4;         // 4M -> total 24M halfs = 48 MB

    prep_kernel<<<dim3(16, 16, 5), 256, 0, stream>>>(x, wq, wk, wv, wo, x16, wt);
    qkv_kernel<<<dim3(8, 32, 3), 512, 0, stream>>>(x16, wt, fcos, fsin,
                                                   Q16, K16, VT16);
    attn_kernel<<<dim3(16, 32), 512, 0, stream>>>(Q16, K16, VT16, A16);
    oproj_kernel<<<dim3(16, 32), 512, 0, stream>>>(A16, wt + 3 * (size_t)DM * DM, out);
}

// Round 8
// 184.939 us; speedup vs baseline: 1.6058x; 1.6058x over previous
//
#include <hip/hip_runtime.h>
#include <math.h>

#define BSZ 2
#define SEQ 2048
#define NH 16
#define DH 64
#define DM 1024
#define HD 1024

typedef _Float16 h16;
typedef _Float16 half8 __attribute__((ext_vector_type(8)));
typedef _Float16 half4 __attribute__((ext_vector_type(4)));
typedef float f32x4 __attribute__((ext_vector_type(4)));
typedef unsigned int u32;
typedef unsigned int u32x2v __attribute__((ext_vector_type(2)));
typedef unsigned int u32x4v __attribute__((ext_vector_type(4)));

__device__ __forceinline__ f32x4 mfma16(half8 a, half8 b, f32x4 c) {
    return __builtin_amdgcn_mfma_f32_16x16x32_f16(a, b, c, 0, 0, 0);
}

// Async global->LDS, 16B per lane. HW writes lane i to ldsbase + i*16.
__device__ __forceinline__ void async_copy16(h16* lds, const h16* g) {
    __builtin_amdgcn_global_load_lds(
        (const __attribute__((address_space(1))) unsigned int*)g,
        (__attribute__((address_space(3))) unsigned int*)lds, 16, 0, 0);
}

// XOR-swizzled chunk offset (halfs) for unpadded 64-half rows (8 chunks).
// 128 B rows -> 2-way max bank aliasing (free). The BK=32 QSWZ variant was
// an 8-way conflict (4.75M conflict cycles, R5/R6) -- do not reuse.
#define SWZ(cb, r) ((((cb) ^ ((r) & 7)) * 8))

// Obuf: [128][64] f32, 16B-chunk XOR swizzle (addr in dwords, c multiple of 4).
#define OBA(r, c) ((r) * 64 + ((((c) >> 2) ^ ((r) & 15)) << 2))

#define EXP2(x) __builtin_amdgcn_exp2f(x)

// Pack two f32 -> one u32 of two f16 (lo = a, hi = b), single v_cvt_pkrtz.
__device__ __forceinline__ u32 pack2(float a, float b) {
    auto p = __builtin_amdgcn_cvt_pkrtz(a, b);
    return __builtin_bit_cast(u32, p);
}

// Swap lane-bit5 (lanes +-32) with the a/b register bit.
__device__ __forceinline__ void pl32swap(u32& a, u32& b) {
#if __has_builtin(__builtin_amdgcn_permlane32_swap)
    u32x2v r = __builtin_amdgcn_permlane32_swap(a, b, false, false);
    a = r.x; b = r.y;
#else
    u32 sa = __builtin_amdgcn_ds_swizzle(a, 0x801F);
    u32 sb = __builtin_amdgcn_ds_swizzle(b, 0x801F);
    bool hi = (threadIdx.x & 32) != 0;
    u32 na = hi ? sb : a;
    u32 nb = hi ? b : sa;
    a = na; b = nb;
#endif
}

// Swap lane-bit4 (lanes +-16) with the a/b register bit.
__device__ __forceinline__ void pl16swap(u32& a, u32& b) {
#if __has_builtin(__builtin_amdgcn_permlane16_swap)
    u32x2v r = __builtin_amdgcn_permlane16_swap(a, b, false, false);
    a = r.x; b = r.y;
#else
    u32 sa = __builtin_amdgcn_ds_swizzle(a, 0x401F);
    u32 sb = __builtin_amdgcn_ds_swizzle(b, 0x401F);
    bool hi = (threadIdx.x & 16) != 0;
    u32 na = hi ? sb : a;
    u32 nb = hi ? b : sa;
    a = na; b = nb;
#endif
}

// ---------------------------------------------------------------------------
// Prep (merged): z<4 -> transpose W[k][n] fp32 to WT[n][k] f16;
//                z==4 -> cvt x fp32 -> f16.
// ---------------------------------------------------------------------------
__global__ __launch_bounds__(256) void prep_kernel(
    const float* __restrict__ x, const float* __restrict__ wq,
    const float* __restrict__ wk, const float* __restrict__ wv,
    const float* __restrict__ wo,
    h16* __restrict__ x16, h16* __restrict__ wt)
{
    const int z = blockIdx.z;
    const int t = threadIdx.x;
    if (z == 4) {
        int flat = blockIdx.y * 16 + blockIdx.x;   // 0..255
#pragma unroll
        for (int i = 0; i < 8; ++i) {
            int idx = flat * 16384 + i * 2048 + t * 8;
            float4 a = *(const float4*)&x[idx];
            float4 b = *(const float4*)&x[idx + 4];
            half8 o;
            o[0] = (h16)a.x; o[1] = (h16)a.y; o[2] = (h16)a.z; o[3] = (h16)a.w;
            o[4] = (h16)b.x; o[5] = (h16)b.y; o[6] = (h16)b.z; o[7] = (h16)b.w;
            *(half8*)&x16[idx] = o;
        }
        return;
    }
    const float* w = (z == 0) ? wq : (z == 1) ? wk : (z == 2) ? wv : wo;
    h16* ot = wt + (size_t)z * DM * DM;
    __shared__ float tile[64][68];
    const int k0 = blockIdx.y * 64, n0 = blockIdx.x * 64;
    const int r = t >> 2, c4 = (t & 3) * 16;
#pragma unroll
    for (int i = 0; i < 16; i += 4) {
        float4 v = *(const float4*)&w[(size_t)(k0 + r) * DM + n0 + c4 + i];
        tile[r][c4 + i + 0] = v.x; tile[r][c4 + i + 1] = v.y;
        tile[r][c4 + i + 2] = v.z; tile[r][c4 + i + 3] = v.w;
    }
    __syncthreads();
#pragma unroll
    for (int g = 0; g < 2; ++g) {
        half8 hh;
#pragma unroll
        for (int j = 0; j < 8; ++j)
            hh[j] = (h16)tile[c4 + g * 8 + j][r];
        *(half8*)&ot[(size_t)(n0 + r) * DM + k0 + c4 + g * 8] = hh;
    }
}

// ---------------------------------------------------------------------------
// Kernel 1: QKV projection + RoPE via MFMA, C^T orientation.
// R2-proven shape: BK=64, SWZ (2-way free), 64 KB dbuf, one exact
// vmcnt(0)+barrier per K-step, prefetch k+64 in flight under step k's MFMAs,
// XCD swizzle. z=0: Q (rope+scale); z=1: K (rope); z=2: V -> [B,H,D,S].
// ---------------------------------------------------------------------------
__global__ __launch_bounds__(512, 4) void qkv_kernel(
    const h16* __restrict__ x16, const h16* __restrict__ wt,
    const float* __restrict__ fcos, const float* __restrict__ fsin,
    h16* __restrict__ Q16, h16* __restrict__ K16, h16* __restrict__ VT16)
{
    // XCD-aware swizzle: 768 blocks, id%8 = XCD -> contiguous chunk of 96.
    const int id  = (blockIdx.z * 32 + blockIdx.y) * 8 + blockIdx.x;
    const int swz = (id & 7) * 96 + (id >> 3);
    const int z   = swz >> 8;
    const int m0  = ((swz >> 3) & 31) * 128;   // s-rows
    const int n0  = (swz & 7) * 128;           // features

    const h16* __restrict__ bw = wt + (size_t)z * DM * DM;

    __shared__ h16 smem[32768];   // 64 KB: 2 x (As 8192 + Bs 8192)
    h16* Vt = smem;               // epilogue alias (17408 halfs < 32768)

    const int t  = threadIdx.x;
    const int w  = t >> 6, ln = t & 63;
    const int L  = ln & 15, U = ln >> 4;
    const int wm = (w & 3) * 32;       // s-subtile
    const int wn = (w >> 2) * 64;      // feature-subtile

    const int sr  = ln >> 3;
    const int scb = (ln & 7) ^ sr;

    f32x4 acc[2][4];
#pragma unroll
    for (int i = 0; i < 2; ++i)
#pragma unroll
        for (int j = 0; j < 4; ++j) acc[i][j] = (f32x4)0.0f;

    // prologue: stage k0=0 into buf0
#pragma unroll
    for (int c = 0; c < 2; ++c) {
        int rb = w * 16 + c * 8;
        async_copy16(&smem[rb * 64],        &x16[(size_t)(m0 + rb + sr) * DM + scb * 8]);
        async_copy16(&smem[8192 + rb * 64], &bw [(size_t)(n0 + rb + sr) * DM + scb * 8]);
    }

    for (int k0 = 0; k0 < DM; k0 += 64) {
        const int buf = (k0 >> 6) & 1;
        h16* As = smem + buf * 16384;
        h16* Bs = As + 8192;

        // only this step's 4 staging loads are outstanding -> vmcnt(0) exact
        __builtin_amdgcn_sched_barrier(0);
        asm volatile("s_waitcnt vmcnt(0)" ::: "memory");
        __builtin_amdgcn_s_barrier();
        __builtin_amdgcn_sched_barrier(0);

        // prefetch k0+64 into other buffer (its readers retired before the
        // barrier above); in flight under this step's MFMAs.
        if (k0 + 64 < DM) {
            h16* An = smem + (buf ^ 1) * 16384;
#pragma unroll
            for (int c = 0; c < 2; ++c) {
                int rb = w * 16 + c * 8;
                async_copy16(&An[rb * 64],
                             &x16[(size_t)(m0 + rb + sr) * DM + k0 + 64 + scb * 8]);
                async_copy16(&An[8192 + rb * 64],
                             &bw [(size_t)(n0 + rb + sr) * DM + k0 + 64 + scb * 8]);
            }
        }

        __builtin_amdgcn_s_setprio(1);
#pragma unroll
        for (int ks = 0; ks < 2; ++ks) {
            half8 af[2], bf[4];
#pragma unroll
            for (int mt = 0; mt < 2; ++mt)
                af[mt] = *(const half8*)&As[(wm + mt * 16 + L) * 64 + SWZ(ks * 4 + U, L)];
#pragma unroll
            for (int nt = 0; nt < 4; ++nt)
                bf[nt] = *(const half8*)&Bs[(wn + nt * 16 + L) * 64 + SWZ(ks * 4 + U, L)];
            // C^T: A=weights (m=feature), B=x (n=s-row)
#pragma unroll
            for (int mt = 0; mt < 2; ++mt)
#pragma unroll
                for (int nt = 0; nt < 4; ++nt)
                    acc[mt][nt] = mfma16(bf[nt], af[mt], acc[mt][nt]);
        }
        __builtin_amdgcn_s_setprio(0);
    }

    const int b = m0 >> 11;
    const int sbase = m0 & 2047;

    // acc[mt][nt][r]: feature = wn+nt*16+U*4+r, s_local = wm+mt*16+L
    if (z < 2) {
        const float sc = (z == 0) ? 0.125f * 1.44269504088896f : 1.0f;
#pragma unroll
        for (int mt = 0; mt < 2; ++mt) {
            int s = sbase + wm + mt * 16 + L;
            const float* ct = &fcos[s * 32];
            const float* st = &fsin[s * 32];
#pragma unroll
            for (int nt = 0; nt < 4; ++nt) {
                int nl = n0 + wn + nt * 16 + U * 4;   // multiple of 4
                int d = nl & 63, h = nl >> 6;
                int pd = d >> 1;
                float cv0 = ct[pd], sv0 = st[pd];
                float cv1 = ct[pd + 1], sv1 = st[pd + 1];
                float v0 = acc[mt][nt][0], v1 = acc[mt][nt][1];
                float v2 = acc[mt][nt][2], v3 = acc[mt][nt][3];
                float o0 = (v0 * cv0 - v1 * sv0) * sc;
                float o1 = (v0 * sv0 + v1 * cv0) * sc;
                float o2 = (v2 * cv1 - v3 * sv1) * sc;
                float o3 = (v2 * sv1 + v3 * cv1) * sc;
                size_t addr = ((size_t)(b * NH + h) * SEQ + s) * DH + d;
                half4 kk;
                kk[0] = (h16)o0; kk[1] = (h16)o1; kk[2] = (h16)o2; kk[3] = (h16)o3;
                if (z == 0) *(half4*)&Q16[addr] = kk;
                else        *(half4*)&K16[addr] = kk;
            }
        }
    } else {
        __syncthreads();  // all frag reads done before Vt reuse
#pragma unroll
        for (int mt = 0; mt < 2; ++mt)
#pragma unroll
            for (int nt = 0; nt < 4; ++nt)
#pragma unroll
                for (int r = 0; r < 4; ++r) {
                    int nloc = wn + nt * 16 + U * 4 + r;
                    int sloc = wm + mt * 16 + L;
                    Vt[nloc * 136 + sloc] = (h16)acc[mt][nt][r];
                }
        __syncthreads();
#pragma unroll
        for (int i = 0; i < 4; ++i) {
            int c = i * 512 + t;     // 0..2047
            int dl = c >> 4;         // 0..127
            int s8 = (c & 15) * 8;
            half8 vv = *(const half8*)&Vt[dl * 136 + s8];
            int n = n0 + dl;
            int d = n & 63, h = n >> 6;
            *(half8*)&VT16[((size_t)(b * NH + h) * DH + d) * SEQ + sbase + s8] = vv;
        }
    }
}

// ---------------------------------------------------------------------------
// Kernel 2: flash attention, paired-wave split-K, NO-MAX softmax.
// R14 = R13 structure with the launch-bounds spill fixed: (512,4) so the
// allocator has its natural ~64-100 VGPR budget (R7's (512,6) forced 40 VGPR
// -> 441 MB scratch spill, 170 us). 48 KB LDS -> LDS allows 3 blocks/CU.
// Ks single-buffered (R8-proven 2-barrier schedule); VTs double-buffered;
// in-register P redistribution (permlane) + cvt_pkrtz.
// ---------------------------------------------------------------------------
__global__ __launch_bounds__(512, 4) void attn_kernel(
    const h16* __restrict__ Q16, const h16* __restrict__ K16,
    const h16* __restrict__ VT16, h16* __restrict__ A16)
{
    __shared__ h16 smem[24576];        // 48 KB exactly
    // Ks: smem[0..8191] ([128][64] swizzled)
    // VTs dbuf: smem+8192 / smem+16384 ([64][128] swizzled each)
    float* lbuf = (float*)smem;            // epilogue alias (Ks region, 1 KB)
    float* Obuf = (float*)(smem + 8192);   // epilogue alias (VTs0+VTs1, 32 KB)

    const int t = threadIdx.x, w = t >> 6, ln = t & 63;
    const int L = ln & 15, U = ln >> 4;
    const int pair = w >> 1, half = w & 1;
    const int qw = pair * 32, kh = half * 64;

    // XCD swizzle: 512 blocks, chunk 64 per XCD -> 4 heads per XCD.
    const int id  = blockIdx.y * 16 + blockIdx.x;
    const int swz = (id & 7) * 64 + (id >> 3);
    const int q0  = (swz & 15) * 128;
    const int bh  = swz >> 4;
    const size_t base = (size_t)bh * SEQ * DH;

    half8 qf[2][2];
#pragma unroll
    for (int qb = 0; qb < 2; ++qb)
#pragma unroll
        for (int ks = 0; ks < 2; ++ks)
            qf[qb][ks] = *(const half8*)&Q16[base + (size_t)(q0 + qw + qb * 16 + L) * DH + ks * 32 + U * 8];

    half8 one8;
#pragma unroll
    for (int i = 0; i < 8; ++i) one8[i] = (h16)1.0f;

    f32x4 O[4][2];
    f32x4 lsum[2];
#pragma unroll
    for (int dt = 0; dt < 4; ++dt)
#pragma unroll
        for (int qb = 0; qb < 2; ++qb) O[dt][qb] = (f32x4)0.0f;
    lsum[0] = (f32x4)0.0f;
    lsum[1] = (f32x4)0.0f;

    const int sr  = ln >> 3;
    const int scb = (ln & 7) ^ sr;

    // ---- prologue: issue K[0] -> Ks, V[0] -> VTs0 ----
#pragma unroll
    for (int c = 0; c < 2; ++c) {
        int rbk = c * 64 + w * 8;
        async_copy16(&smem[rbk * 64], &K16[base + (size_t)(rbk + sr) * DH + scb * 8]);
    }
#pragma unroll
    for (int c = 0; c < 2; ++c) {
        int rv = (w * 2 + c) * 4;
        int c16 = (ln & 15) ^ ((rv + U) & 15);
        async_copy16(&smem[8192 + rv * 128], &VT16[base + (size_t)(rv + U) * SEQ + c16 * 8]);
    }

    for (int j0 = 0; j0 < SEQ; j0 += 128) {
        const int buf = (j0 >> 7) & 1;
        h16* VTcur = smem + 8192 + buf * 8192;

        // Outstanding: K[j] (2) + V[j] (2) only -> vmcnt(0) exact.
        __builtin_amdgcn_sched_barrier(0);
        asm volatile("s_waitcnt vmcnt(0)" ::: "memory");
        __builtin_amdgcn_s_barrier();
        __builtin_amdgcn_sched_barrier(0);

        // prefetch V[j+1] into the other VTs buffer (its iter j-1 readers
        // retired before the barrier above).
        if (j0 + 128 < SEQ) {
            h16* Vnxt = smem + 8192 + (buf ^ 1) * 8192;
#pragma unroll
            for (int c = 0; c < 2; ++c) {
                int rv = (w * 2 + c) * 4;
                int c16 = (ln & 15) ^ ((rv + U) & 15);
                async_copy16(&Vnxt[rv * 128],
                             &VT16[base + (size_t)(rv + U) * SEQ + (j0 + 128) + c16 * 8]);
            }
        }

        // S^T = K Q^T on this wave's k-half (reads Ks)
        f32x4 S[4][2];
        __builtin_amdgcn_s_setprio(1);
#pragma unroll
        for (int nt = 0; nt < 4; ++nt) {
            S[nt][0] = (f32x4)0.0f;
            S[nt][1] = (f32x4)0.0f;
#pragma unroll
            for (int ks = 0; ks < 2; ++ks) {
                half8 kf = *(const half8*)&smem[(kh + nt * 16 + L) * 64 + SWZ(ks * 4 + U, L)];
                S[nt][0] = mfma16(kf, qf[0][ks], S[nt][0]);
                S[nt][1] = mfma16(kf, qf[1][ks], S[nt][1]);
            }
        }
        __builtin_amdgcn_s_setprio(0);

        // all Ks ds_reads retired chip-wide before K[j+1] overwrites Ks.
        __builtin_amdgcn_sched_barrier(0);
        asm volatile("s_waitcnt lgkmcnt(0)" ::: "memory");
        __builtin_amdgcn_sched_barrier(0);
        __builtin_amdgcn_s_barrier();

        // issue K[j+1] over Ks; in flight through exp/PV and next QK wait.
        if (j0 + 128 < SEQ) {
#pragma unroll
            for (int c = 0; c < 2; ++c) {
                int rbk = c * 64 + w * 8;
                async_copy16(&smem[rbk * 64],
                             &K16[base + (size_t)(j0 + 128 + rbk + sr) * DH + scb * 8]);
            }
        }

        // no-max softmax p = exp2(S), redistribute C-layout -> B-layout
        // entirely in registers (permlane32/16_swap; R10 derivation).
        half8 pf[2][2];
#pragma unroll
        for (int qb = 0; qb < 2; ++qb) {
            u32 X[2][2][2];   // [k5][bit=k3][p=k1]
#pragma unroll
            for (int k5 = 0; k5 < 2; ++k5)
#pragma unroll
                for (int p = 0; p < 2; ++p) {
                    u32 a = pack2(EXP2(S[k5 * 2 + 0][qb][2 * p]),
                                  EXP2(S[k5 * 2 + 0][qb][2 * p + 1]));
                    u32 b = pack2(EXP2(S[k5 * 2 + 1][qb][2 * p]),
                                  EXP2(S[k5 * 2 + 1][qb][2 * p + 1]));
                    pl32swap(a, b);
                    X[k5][0][p] = a; X[k5][1][p] = b;
                }
#pragma unroll
            for (int k5 = 0; k5 < 2; ++k5) {
                u32x4v uv;
#pragma unroll
                for (int p = 0; p < 2; ++p) {
                    u32 a = X[k5][0][p], b = X[k5][1][p];
                    pl16swap(a, b);
                    uv[p]     = a;   // (k2=0, k1=p)
                    uv[2 + p] = b;   // (k2=1, k1=p)
                }
                pf[qb][k5] = __builtin_bit_cast(half8, uv);
            }
        }

        // O^T += V^T P ; l += ones^T P (via MFMA), reads VTs[j&1]
        __builtin_amdgcn_s_setprio(1);
#pragma unroll
        for (int dt = 0; dt < 4; ++dt)
#pragma unroll
            for (int ks2 = 0; ks2 < 2; ++ks2) {
                half8 vf = *(const half8*)&VTcur[(dt * 16 + L) * 128 + ((half * 8 + ks2 * 4 + U) ^ L) * 8];
                O[dt][0] = mfma16(vf, pf[0][ks2], O[dt][0]);
                O[dt][1] = mfma16(vf, pf[1][ks2], O[dt][1]);
            }
#pragma unroll
        for (int ks2 = 0; ks2 < 2; ++ks2) {
            lsum[0] = mfma16(one8, pf[0][ks2], lsum[0]);
            lsum[1] = mfma16(one8, pf[1][ks2], lsum[1]);
        }
        __builtin_amdgcn_s_setprio(0);
    }

    // ---- cross-half combine (plain sums) ----
    // lbuf aliases Ks (all Ks reads retired at last mid-iter lgkm+barrier; no
    // K[16] issued). Obuf aliases VTs0+VTs1; writes happen after the first
    // __syncthreads (all PV reads drained), disjoint from lbuf.
    if (U == 0) {
        lbuf[w * 32 + L]      = lsum[0][0];
        lbuf[w * 32 + 16 + L] = lsum[1][0];
    }
    __syncthreads();
    const int pw = w ^ 1;
    float l_tot[2];
    l_tot[0] = lsum[0][0] + lbuf[pw * 32 + L];
    l_tot[1] = lsum[1][0] + lbuf[pw * 32 + 16 + L];

    if (half) {
#pragma unroll
        for (int qb = 0; qb < 2; ++qb)
#pragma unroll
            for (int dt = 0; dt < 4; ++dt)
                *(f32x4*)&Obuf[OBA(qw + qb * 16 + L, dt * 16 + U * 4)] = O[dt][qb];
    }
    __syncthreads();
    if (!half) {
        const int b = bh >> 4, hh = bh & 15;
#pragma unroll
        for (int qb = 0; qb < 2; ++qb) {
            float inv = 1.0f / l_tot[qb];
            int s = q0 + qw + qb * 16 + L;
#pragma unroll
            for (int dt = 0; dt < 4; ++dt) {
                f32x4 op = *(const f32x4*)&Obuf[OBA(qw + qb * 16 + L, dt * 16 + U * 4)];
                half4 o4;
#pragma unroll
                for (int r = 0; r < 4; ++r)
                    o4[r] = (h16)((O[dt][qb][r] + op[r]) * inv);
                *(half4*)&A16[(size_t)(b * SEQ + s) * HD + hh * DH + dt * 16 + U * 4] = o4;
            }
        }
    }
}

// ---------------------------------------------------------------------------
// Kernel 3: output projection, 128x64 tiles, 512 threads = 8 waves,
// wave-tile 16x64, BK=64. Triple-buffered depth-2 prefetch (72 KB ->
// 2 blocks/CU, grid = exactly 2/CU). vmcnt(3): 3 loads/thread/step.
// ---------------------------------------------------------------------------
__global__ __launch_bounds__(512, 4) void oproj_kernel(
    const h16* __restrict__ A16, const h16* __restrict__ bw,
    float* __restrict__ out)
{
    __shared__ h16 smem[36864];   // 72 KB: 3 x (As 8192 + Bs 4096)

    // XCD swizzle: 512 blocks, chunk 64 per XCD.
    const int id  = blockIdx.y * 16 + blockIdx.x;
    const int swz = (id & 7) * 64 + (id >> 3);
    const int n0  = (swz & 15) * 64;
    const int m0  = (swz >> 4) * 128;

    const int t  = threadIdx.x;
    const int w  = t >> 6, ln = t & 63;
    const int L  = ln & 15, U = ln >> 4;

    const int sr  = ln >> 3;
    const int scb = (ln & 7) ^ sr;

    f32x4 acc[4];
#pragma unroll
    for (int j = 0; j < 4; ++j) acc[j] = (f32x4)0.0f;

    // per-thread: 3 loads per step (2 A chunks + 1 B chunk)
    auto stage = [&](int buf, int kk) {
        h16* dst = smem + buf * 12288;
#pragma unroll
        for (int c = 0; c < 2; ++c) {
            int rb = w * 16 + c * 8;
            async_copy16(&dst[rb * 64], &A16[(size_t)(m0 + rb + sr) * DM + kk + scb * 8]);
        }
        async_copy16(&dst[8192 + (w * 8) * 64], &bw[(size_t)(n0 + w * 8 + sr) * DM + kk + scb * 8]);
    };

    // prologue: issue steps 0 and 1
    stage(0, 0);
    stage(1, 64);

    int step = 0;
    for (int k0 = 0; k0 < DM; k0 += 64, ++step) {
        const int buf = step - (step / 3) * 3;   // step % 3
        h16* As = smem + buf * 12288;
        h16* Bs = As + 8192;

        // outstanding: step k (3) + step k+1 (3) = 6 -> vmcnt(3) keeps k+1's
        // loads in flight across the barrier. Last step: vmcnt(0).
        __builtin_amdgcn_sched_barrier(0);
        if (k0 + 64 < DM) asm volatile("s_waitcnt vmcnt(3)" ::: "memory");
        else              asm volatile("s_waitcnt vmcnt(0)" ::: "memory");
        __builtin_amdgcn_s_barrier();
        __builtin_amdgcn_sched_barrier(0);

        if (k0 + 128 < DM) {
            int nb = step + 2;
            stage(nb - (nb / 3) * 3, k0 + 128);
        }

        __builtin_amdgcn_s_setprio(1);
#pragma unroll
        for (int ks = 0; ks < 2; ++ks) {
            half8 af, bf[4];
            af = *(const half8*)&As[(w * 16 + L) * 64 + SWZ(ks * 4 + U, L)];
#pragma unroll
            for (int nt = 0; nt < 4; ++nt)
                bf[nt] = *(const half8*)&Bs[(nt * 16 + L) * 64 + SWZ(ks * 4 + U, L)];
#pragma unroll
            for (int nt = 0; nt < 4; ++nt)
                acc[nt] = mfma16(af, bf[nt], acc[nt]);
        }
        __builtin_amdgcn_s_setprio(0);
    }

#pragma unroll
    for (int nt = 0; nt < 4; ++nt)
#pragma unroll
        for (int r = 0; r < 4; ++r) {
            int row = m0 + w * 16 + U * 4 + r;
            int col = n0 + nt * 16 + L;
            out[(size_t)row * DM + col] = acc[nt][r];
        }
}

extern "C" void kernel_launch(void* const* d_in, const int* in_sizes, int n_in,
                              void* d_out, int out_size, void* d_ws, size_t ws_size,
                              hipStream_t stream)
{
    const float* x    = (const float*)d_in[0];
    const float* fcos = (const float*)d_in[1];
    const float* fsin = (const float*)d_in[2];
    const float* wq   = (const float*)d_in[3];
    const float* wk   = (const float*)d_in[4];
    const float* wv   = (const float*)d_in[5];
    const float* wo   = (const float*)d_in[6];
    float* out = (float*)d_out;

    const size_t M4 = (size_t)4 * 1024 * 1024;
    h16* x16  = (h16*)d_ws;        // 4M halfs
    h16* wt   = x16 + M4;          // 4M (4 matrices, [n][k])
    h16* Q16  = wt + M4;           // 4M
    h16* K16  = Q16 + M4;          // 4M
    h16* VT16 = K16 + M4;          // 4M ([B,H,D,S])
    h16* A16  = VT16 + M4;         // 4M -> total 24M halfs = 48 MB

    prep_kernel<<<dim3(16, 16, 5), 256, 0, stream>>>(x, wq, wk, wv, wo, x16, wt);
    qkv_kernel<<<dim3(8, 32, 3), 512, 0, stream>>>(x16, wt, fcos, fsin,
                                                   Q16, K16, VT16);
    attn_kernel<<<dim3(16, 32), 512, 0, stream>>>(Q16, K16, VT16, A16);
    oproj_kernel<<<dim3(16, 32), 512, 0, stream>>>(A16, wt + 3 * (size_t)DM * DM, out);
}

// Round 9
// 180.416 us; speedup vs baseline: 1.6460x; 1.0251x over previous
//
#include <hip/hip_runtime.h>
#include <math.h>

#define BSZ 2
#define SEQ 2048
#define NH 16
#define DH 64
#define DM 1024
#define HD 1024

typedef _Float16 h16;
typedef _Float16 half8 __attribute__((ext_vector_type(8)));
typedef _Float16 half4 __attribute__((ext_vector_type(4)));
typedef float f32x4 __attribute__((ext_vector_type(4)));
typedef unsigned int u32;
typedef unsigned int u32x2v __attribute__((ext_vector_type(2)));
typedef unsigned int u32x4v __attribute__((ext_vector_type(4)));

__device__ __forceinline__ f32x4 mfma16(half8 a, half8 b, f32x4 c) {
    return __builtin_amdgcn_mfma_f32_16x16x32_f16(a, b, c, 0, 0, 0);
}

// Async global->LDS, 16B per lane. HW writes lane i to ldsbase + i*16.
__device__ __forceinline__ void async_copy16(h16* lds, const h16* g) {
    __builtin_amdgcn_global_load_lds(
        (const __attribute__((address_space(1))) unsigned int*)g,
        (__attribute__((address_space(3))) unsigned int*)lds, 16, 0, 0);
}

// XOR-swizzled chunk offset (halfs) for unpadded 64-half rows (8 chunks).
// 128 B rows -> 2-way max bank aliasing (free). The BK=32 QSWZ variant was
// an 8-way conflict (4.75M conflict cycles, R5/R6) -- do not reuse.
#define SWZ(cb, r) ((((cb) ^ ((r) & 7)) * 8))

// Obuf: [128][64] f32, 16B-chunk XOR swizzle (addr in dwords, c multiple of 4).
#define OBA(r, c) ((r) * 64 + ((((c) >> 2) ^ ((r) & 15)) << 2))

#define EXP2(x) __builtin_amdgcn_exp2f(x)

// Pack two f32 -> one u32 of two f16 (lo = a, hi = b), single v_cvt_pkrtz.
__device__ __forceinline__ u32 pack2(float a, float b) {
    auto p = __builtin_amdgcn_cvt_pkrtz(a, b);
    return __builtin_bit_cast(u32, p);
}

// Swap lane-bit5 (lanes +-32) with the a/b register bit.
__device__ __forceinline__ void pl32swap(u32& a, u32& b) {
#if __has_builtin(__builtin_amdgcn_permlane32_swap)
    u32x2v r = __builtin_amdgcn_permlane32_swap(a, b, false, false);
    a = r.x; b = r.y;
#else
    u32 sa = __builtin_amdgcn_ds_swizzle(a, 0x801F);
    u32 sb = __builtin_amdgcn_ds_swizzle(b, 0x801F);
    bool hi = (threadIdx.x & 32) != 0;
    u32 na = hi ? sb : a;
    u32 nb = hi ? b : sa;
    a = na; b = nb;
#endif
}

// Swap lane-bit4 (lanes +-16) with the a/b register bit.
__device__ __forceinline__ void pl16swap(u32& a, u32& b) {
#if __has_builtin(__builtin_amdgcn_permlane16_swap)
    u32x2v r = __builtin_amdgcn_permlane16_swap(a, b, false, false);
    a = r.x; b = r.y;
#else
    u32 sa = __builtin_amdgcn_ds_swizzle(a, 0x401F);
    u32 sb = __builtin_amdgcn_ds_swizzle(b, 0x401F);
    bool hi = (threadIdx.x & 16) != 0;
    u32 na = hi ? sb : a;
    u32 nb = hi ? b : sa;
    a = na; b = nb;
#endif
}

// ---------------------------------------------------------------------------
// Prep (merged): z<4 -> transpose W[k][n] fp32 to WT[n][k] f16;
//                z==4 -> cvt x fp32 -> f16.
// ---------------------------------------------------------------------------
__global__ __launch_bounds__(256) void prep_kernel(
    const float* __restrict__ x, const float* __restrict__ wq,
    const float* __restrict__ wk, const float* __restrict__ wv,
    const float* __restrict__ wo,
    h16* __restrict__ x16, h16* __restrict__ wt)
{
    const int z = blockIdx.z;
    const int t = threadIdx.x;
    if (z == 4) {
        int flat = blockIdx.y * 16 + blockIdx.x;   // 0..255
#pragma unroll
        for (int i = 0; i < 8; ++i) {
            int idx = flat * 16384 + i * 2048 + t * 8;
            float4 a = *(const float4*)&x[idx];
            float4 b = *(const float4*)&x[idx + 4];
            half8 o;
            o[0] = (h16)a.x; o[1] = (h16)a.y; o[2] = (h16)a.z; o[3] = (h16)a.w;
            o[4] = (h16)b.x; o[5] = (h16)b.y; o[6] = (h16)b.z; o[7] = (h16)b.w;
            *(half8*)&x16[idx] = o;
        }
        return;
    }
    const float* w = (z == 0) ? wq : (z == 1) ? wk : (z == 2) ? wv : wo;
    h16* ot = wt + (size_t)z * DM * DM;
    __shared__ float tile[64][68];
    const int k0 = blockIdx.y * 64, n0 = blockIdx.x * 64;
    const int r = t >> 2, c4 = (t & 3) * 16;
#pragma unroll
    for (int i = 0; i < 16; i += 4) {
        float4 v = *(const float4*)&w[(size_t)(k0 + r) * DM + n0 + c4 + i];
        tile[r][c4 + i + 0] = v.x; tile[r][c4 + i + 1] = v.y;
        tile[r][c4 + i + 2] = v.z; tile[r][c4 + i + 3] = v.w;
    }
    __syncthreads();
#pragma unroll
    for (int g = 0; g < 2; ++g) {
        half8 hh;
#pragma unroll
        for (int j = 0; j < 8; ++j)
            hh[j] = (h16)tile[c4 + g * 8 + j][r];
        *(half8*)&ot[(size_t)(n0 + r) * DM + k0 + c4 + g * 8] = hh;
    }
}

// ---------------------------------------------------------------------------
// Kernel 1: QKV projection + RoPE, z-MERGED (R15): one block computes Q, K,
// and V for the same (m0, n0f) -> x-tile staged ONCE feeds 3 B-tiles,
// 48 MFMA/wave/step (3x per barrier), grid = 256 blocks = exactly 1/CU
// (one residency round, no tail). LDS 128 KB: 2 x (A 16 KB + 3 x B 16 KB).
// R2-proven schedule: depth-1 dbuf, one exact vmcnt(0)+barrier per step,
// prefetch in flight under the step's MFMAs. XCD swizzle: each XCD owns one
// n-column -> its weight tiles fetched once per XCD.
// launch_bounds(512,2): 1 block x 8 waves = 2/SIMD; 256-VGPR cap (acc=96,
// frags ~40, no spill; NEVER tighten to (512,4+) -- R7 spill lesson).
// ---------------------------------------------------------------------------
__global__ __launch_bounds__(512, 2) void qkv_kernel(
    const h16* __restrict__ x16, const h16* __restrict__ wt,
    const float* __restrict__ fcos, const float* __restrict__ fsin,
    h16* __restrict__ Q16, h16* __restrict__ K16, h16* __restrict__ VT16)
{
    // XCD swizzle: 256 blocks, id%8 = XCD, chunk of 32. n-block = swz>>5
    // (constant per XCD), m-block = swz&31.
    const int id  = blockIdx.x;
    const int swz = (id & 7) * 32 + (id >> 3);
    const int m0  = (swz & 31) * 128;    // s-rows
    const int n0  = (swz >> 5) * 128;    // features (XCD-constant)

    __shared__ h16 smem[65536];   // 128 KB: 2 x (As 8192 + Bs 3x8192)
    h16* Vt = smem;               // epilogue alias (17408 halfs << 65536)

    const int t  = threadIdx.x;
    const int w  = t >> 6, ln = t & 63;
    const int L  = ln & 15, U = ln >> 4;
    const int wm = (w & 3) * 32;       // s-subtile
    const int wn = (w >> 2) * 64;      // feature-subtile

    const int sr  = ln >> 3;
    const int scb = (ln & 7) ^ sr;

    f32x4 acc[3][2][4];
#pragma unroll
    for (int z = 0; z < 3; ++z)
#pragma unroll
        for (int i = 0; i < 2; ++i)
#pragma unroll
            for (int j = 0; j < 4; ++j) acc[z][i][j] = (f32x4)0.0f;

    // per-thread staging: 2 copies for A + 2 per weight matrix = 8/step.
    auto stage = [&](int buf, int kk) {
        h16* dst = smem + buf * 32768;
#pragma unroll
        for (int c = 0; c < 2; ++c) {
            int rb = w * 16 + c * 8;
            async_copy16(&dst[rb * 64],
                         &x16[(size_t)(m0 + rb + sr) * DM + kk + scb * 8]);
#pragma unroll
            for (int z = 0; z < 3; ++z)
                async_copy16(&dst[8192 + z * 8192 + rb * 64],
                             &wt[(size_t)z * DM * DM + (size_t)(n0 + rb + sr) * DM + kk + scb * 8]);
        }
    };

    // prologue: stage k0=0 into buf0
    stage(0, 0);

    for (int k0 = 0; k0 < DM; k0 += 64) {
        const int buf = (k0 >> 6) & 1;
        h16* As = smem + buf * 32768;

        // only this step's 8 staging loads are outstanding -> vmcnt(0) exact
        __builtin_amdgcn_sched_barrier(0);
        asm volatile("s_waitcnt vmcnt(0)" ::: "memory");
        __builtin_amdgcn_s_barrier();
        __builtin_amdgcn_sched_barrier(0);

        // prefetch k0+64 into other buffer (its readers retired before the
        // barrier above); in flight under this step's 48 MFMAs.
        if (k0 + 64 < DM) stage(buf ^ 1, k0 + 64);

        __builtin_amdgcn_s_setprio(1);
#pragma unroll
        for (int ks = 0; ks < 2; ++ks) {
            half8 af[2];
#pragma unroll
            for (int mt = 0; mt < 2; ++mt)
                af[mt] = *(const half8*)&As[(wm + mt * 16 + L) * 64 + SWZ(ks * 4 + U, L)];
#pragma unroll
            for (int z = 0; z < 3; ++z) {
                const h16* Bs = As + 8192 + z * 8192;
                half8 bf[4];
#pragma unroll
                for (int nt = 0; nt < 4; ++nt)
                    bf[nt] = *(const half8*)&Bs[(wn + nt * 16 + L) * 64 + SWZ(ks * 4 + U, L)];
                // C^T: A=weights (m=feature), B=x (n=s-row)
#pragma unroll
                for (int mt = 0; mt < 2; ++mt)
#pragma unroll
                    for (int nt = 0; nt < 4; ++nt)
                        acc[z][mt][nt] = mfma16(bf[nt], af[mt], acc[z][mt][nt]);
            }
        }
        __builtin_amdgcn_s_setprio(0);
    }

    const int b = m0 >> 11;
    const int sbase = m0 & 2047;

    // ---- Q and K epilogues (rope; registers only) ----
#pragma unroll
    for (int zz = 0; zz < 2; ++zz) {
        const float sc = (zz == 0) ? 0.125f * 1.44269504088896f : 1.0f;
        h16* dst = (zz == 0) ? Q16 : K16;
#pragma unroll
        for (int mt = 0; mt < 2; ++mt) {
            int s = sbase + wm + mt * 16 + L;
            const float* ct = &fcos[s * 32];
            const float* st = &fsin[s * 32];
#pragma unroll
            for (int nt = 0; nt < 4; ++nt) {
                int nl = n0 + wn + nt * 16 + U * 4;   // multiple of 4
                int d = nl & 63, h = nl >> 6;
                int pd = d >> 1;
                float cv0 = ct[pd], sv0 = st[pd];
                float cv1 = ct[pd + 1], sv1 = st[pd + 1];
                float v0 = acc[zz][mt][nt][0], v1 = acc[zz][mt][nt][1];
                float v2 = acc[zz][mt][nt][2], v3 = acc[zz][mt][nt][3];
                float o0 = (v0 * cv0 - v1 * sv0) * sc;
                float o1 = (v0 * sv0 + v1 * cv0) * sc;
                float o2 = (v2 * cv1 - v3 * sv1) * sc;
                float o3 = (v2 * sv1 + v3 * cv1) * sc;
                size_t addr = ((size_t)(b * NH + h) * SEQ + s) * DH + d;
                half4 kk;
                kk[0] = (h16)o0; kk[1] = (h16)o1; kk[2] = (h16)o2; kk[3] = (h16)o3;
                *(half4*)&dst[addr] = kk;
            }
        }
    }

    // ---- V epilogue: LDS transpose -> VT16 [B,H,D,S] ----
    __syncthreads();  // all frag reads + staging drained before Vt reuse
#pragma unroll
    for (int mt = 0; mt < 2; ++mt)
#pragma unroll
        for (int nt = 0; nt < 4; ++nt)
#pragma unroll
            for (int r = 0; r < 4; ++r) {
                int nloc = wn + nt * 16 + U * 4 + r;
                int sloc = wm + mt * 16 + L;
                Vt[nloc * 136 + sloc] = (h16)acc[2][mt][nt][r];
            }
    __syncthreads();
#pragma unroll
    for (int i = 0; i < 4; ++i) {
        int c = i * 512 + t;     // 0..2047
        int dl = c >> 4;         // 0..127
        int s8 = (c & 15) * 8;
        half8 vv = *(const half8*)&Vt[dl * 136 + s8];
        int n = n0 + dl;
        int d = n & 63, h = n >> 6;
        *(half8*)&VT16[((size_t)(b * NH + h) * DH + d) * SEQ + sbase + s8] = vv;
    }
}

// ---------------------------------------------------------------------------
// Kernel 2: flash attention, paired-wave split-K, NO-MAX softmax.
// R14 structure (best measured: 44.9 us): (512,4) natural VGPR budget,
// 48 KB LDS, Ks single-buffered (2-barrier schedule), VTs double-buffered,
// in-register P redistribution (permlane) + cvt_pkrtz.
// ---------------------------------------------------------------------------
__global__ __launch_bounds__(512, 4) void attn_kernel(
    const h16* __restrict__ Q16, const h16* __restrict__ K16,
    const h16* __restrict__ VT16, h16* __restrict__ A16)
{
    __shared__ h16 smem[24576];        // 48 KB exactly
    // Ks: smem[0..8191] ([128][64] swizzled)
    // VTs dbuf: smem+8192 / smem+16384 ([64][128] swizzled each)
    float* lbuf = (float*)smem;            // epilogue alias (Ks region, 1 KB)
    float* Obuf = (float*)(smem + 8192);   // epilogue alias (VTs0+VTs1, 32 KB)

    const int t = threadIdx.x, w = t >> 6, ln = t & 63;
    const int L = ln & 15, U = ln >> 4;
    const int pair = w >> 1, half = w & 1;
    const int qw = pair * 32, kh = half * 64;

    // XCD swizzle: 512 blocks, chunk 64 per XCD -> 4 heads per XCD.
    const int id  = blockIdx.y * 16 + blockIdx.x;
    const int swz = (id & 7) * 64 + (id >> 3);
    const int q0  = (swz & 15) * 128;
    const int bh  = swz >> 4;
    const size_t base = (size_t)bh * SEQ * DH;

    half8 qf[2][2];
#pragma unroll
    for (int qb = 0; qb < 2; ++qb)
#pragma unroll
        for (int ks = 0; ks < 2; ++ks)
            qf[qb][ks] = *(const half8*)&Q16[base + (size_t)(q0 + qw + qb * 16 + L) * DH + ks * 32 + U * 8];

    half8 one8;
#pragma unroll
    for (int i = 0; i < 8; ++i) one8[i] = (h16)1.0f;

    f32x4 O[4][2];
    f32x4 lsum[2];
#pragma unroll
    for (int dt = 0; dt < 4; ++dt)
#pragma unroll
        for (int qb = 0; qb < 2; ++qb) O[dt][qb] = (f32x4)0.0f;
    lsum[0] = (f32x4)0.0f;
    lsum[1] = (f32x4)0.0f;

    const int sr  = ln >> 3;
    const int scb = (ln & 7) ^ sr;

    // ---- prologue: issue K[0] -> Ks, V[0] -> VTs0 ----
#pragma unroll
    for (int c = 0; c < 2; ++c) {
        int rbk = c * 64 + w * 8;
        async_copy16(&smem[rbk * 64], &K16[base + (size_t)(rbk + sr) * DH + scb * 8]);
    }
#pragma unroll
    for (int c = 0; c < 2; ++c) {
        int rv = (w * 2 + c) * 4;
        int c16 = (ln & 15) ^ ((rv + U) & 15);
        async_copy16(&smem[8192 + rv * 128], &VT16[base + (size_t)(rv + U) * SEQ + c16 * 8]);
    }

    for (int j0 = 0; j0 < SEQ; j0 += 128) {
        const int buf = (j0 >> 7) & 1;
        h16* VTcur = smem + 8192 + buf * 8192;

        // Outstanding: K[j] (2) + V[j] (2) only -> vmcnt(0) exact.
        __builtin_amdgcn_sched_barrier(0);
        asm volatile("s_waitcnt vmcnt(0)" ::: "memory");
        __builtin_amdgcn_s_barrier();
        __builtin_amdgcn_sched_barrier(0);

        // prefetch V[j+1] into the other VTs buffer (its iter j-1 readers
        // retired before the barrier above).
        if (j0 + 128 < SEQ) {
            h16* Vnxt = smem + 8192 + (buf ^ 1) * 8192;
#pragma unroll
            for (int c = 0; c < 2; ++c) {
                int rv = (w * 2 + c) * 4;
                int c16 = (ln & 15) ^ ((rv + U) & 15);
                async_copy16(&Vnxt[rv * 128],
                             &VT16[base + (size_t)(rv + U) * SEQ + (j0 + 128) + c16 * 8]);
            }
        }

        // S^T = K Q^T on this wave's k-half (reads Ks)
        f32x4 S[4][2];
        __builtin_amdgcn_s_setprio(1);
#pragma unroll
        for (int nt = 0; nt < 4; ++nt) {
            S[nt][0] = (f32x4)0.0f;
            S[nt][1] = (f32x4)0.0f;
#pragma unroll
            for (int ks = 0; ks < 2; ++ks) {
                half8 kf = *(const half8*)&smem[(kh + nt * 16 + L) * 64 + SWZ(ks * 4 + U, L)];
                S[nt][0] = mfma16(kf, qf[0][ks], S[nt][0]);
                S[nt][1] = mfma16(kf, qf[1][ks], S[nt][1]);
            }
        }
        __builtin_amdgcn_s_setprio(0);

        // all Ks ds_reads retired chip-wide before K[j+1] overwrites Ks.
        __builtin_amdgcn_sched_barrier(0);
        asm volatile("s_waitcnt lgkmcnt(0)" ::: "memory");
        __builtin_amdgcn_sched_barrier(0);
        __builtin_amdgcn_s_barrier();

        // issue K[j+1] over Ks; in flight through exp/PV and next QK wait.
        if (j0 + 128 < SEQ) {
#pragma unroll
            for (int c = 0; c < 2; ++c) {
                int rbk = c * 64 + w * 8;
                async_copy16(&smem[rbk * 64],
                             &K16[base + (size_t)(j0 + 128 + rbk + sr) * DH + scb * 8]);
            }
        }

        // no-max softmax p = exp2(S), redistribute C-layout -> B-layout
        // entirely in registers (permlane32/16_swap; R10 derivation).
        half8 pf[2][2];
#pragma unroll
        for (int qb = 0; qb < 2; ++qb) {
            u32 X[2][2][2];   // [k5][bit=k3][p=k1]
#pragma unroll
            for (int k5 = 0; k5 < 2; ++k5)
#pragma unroll
                for (int p = 0; p < 2; ++p) {
                    u32 a = pack2(EXP2(S[k5 * 2 + 0][qb][2 * p]),
                                  EXP2(S[k5 * 2 + 0][qb][2 * p + 1]));
                    u32 b = pack2(EXP2(S[k5 * 2 + 1][qb][2 * p]),
                                  EXP2(S[k5 * 2 + 1][qb][2 * p + 1]));
                    pl32swap(a, b);
                    X[k5][0][p] = a; X[k5][1][p] = b;
                }
#pragma unroll
            for (int k5 = 0; k5 < 2; ++k5) {
                u32x4v uv;
#pragma unroll
                for (int p = 0; p < 2; ++p) {
                    u32 a = X[k5][0][p], b = X[k5][1][p];
                    pl16swap(a, b);
                    uv[p]     = a;   // (k2=0, k1=p)
                    uv[2 + p] = b;   // (k2=1, k1=p)
                }
                pf[qb][k5] = __builtin_bit_cast(half8, uv);
            }
        }

        // O^T += V^T P ; l += ones^T P (via MFMA), reads VTs[j&1]
        __builtin_amdgcn_s_setprio(1);
#pragma unroll
        for (int dt = 0; dt < 4; ++dt)
#pragma unroll
            for (int ks2 = 0; ks2 < 2; ++ks2) {
                half8 vf = *(const half8*)&VTcur[(dt * 16 + L) * 128 + ((half * 8 + ks2 * 4 + U) ^ L) * 8];
                O[dt][0] = mfma16(vf, pf[0][ks2], O[dt][0]);
                O[dt][1] = mfma16(vf, pf[1][ks2], O[dt][1]);
            }
#pragma unroll
        for (int ks2 = 0; ks2 < 2; ++ks2) {
            lsum[0] = mfma16(one8, pf[0][ks2], lsum[0]);
            lsum[1] = mfma16(one8, pf[1][ks2], lsum[1]);
        }
        __builtin_amdgcn_s_setprio(0);
    }

    // ---- cross-half combine (plain sums) ----
    if (U == 0) {
        lbuf[w * 32 + L]      = lsum[0][0];
        lbuf[w * 32 + 16 + L] = lsum[1][0];
    }
    __syncthreads();
    const int pw = w ^ 1;
    float l_tot[2];
    l_tot[0] = lsum[0][0] + lbuf[pw * 32 + L];
    l_tot[1] = lsum[1][0] + lbuf[pw * 32 + 16 + L];

    if (half) {
#pragma unroll
        for (int qb = 0; qb < 2; ++qb)
#pragma unroll
            for (int dt = 0; dt < 4; ++dt)
                *(f32x4*)&Obuf[OBA(qw + qb * 16 + L, dt * 16 + U * 4)] = O[dt][qb];
    }
    __syncthreads();
    if (!half) {
        const int b = bh >> 4, hh = bh & 15;
#pragma unroll
        for (int qb = 0; qb < 2; ++qb) {
            float inv = 1.0f / l_tot[qb];
            int s = q0 + qw + qb * 16 + L;
#pragma unroll
            for (int dt = 0; dt < 4; ++dt) {
                f32x4 op = *(const f32x4*)&Obuf[OBA(qw + qb * 16 + L, dt * 16 + U * 4)];
                half4 o4;
#pragma unroll
                for (int r = 0; r < 4; ++r)
                    o4[r] = (h16)((O[dt][qb][r] + op[r]) * inv);
                *(half4*)&A16[(size_t)(b * SEQ + s) * HD + hh * DH + dt * 16 + U * 4] = o4;
            }
        }
    }
}

// ---------------------------------------------------------------------------
// Kernel 3: output projection, 128x64 tiles, 512 threads = 8 waves,
// wave-tile 16x64, BK=64. Triple-buffered depth-2 prefetch (72 KB ->
// 2 blocks/CU, grid = exactly 2/CU). vmcnt(3): 3 loads/thread/step.
// ---------------------------------------------------------------------------
__global__ __launch_bounds__(512, 4) void oproj_kernel(
    const h16* __restrict__ A16, const h16* __restrict__ bw,
    float* __restrict__ out)
{
    __shared__ h16 smem[36864];   // 72 KB: 3 x (As 8192 + Bs 4096)

    // XCD swizzle: 512 blocks, chunk 64 per XCD.
    const int id  = blockIdx.y * 16 + blockIdx.x;
    const int swz = (id & 7) * 64 + (id >> 3);
    const int n0  = (swz & 15) * 64;
    const int m0  = (swz >> 4) * 128;

    const int t  = threadIdx.x;
    const int w  = t >> 6, ln = t & 63;
    const int L  = ln & 15, U = ln >> 4;

    const int sr  = ln >> 3;
    const int scb = (ln & 7) ^ sr;

    f32x4 acc[4];
#pragma unroll
    for (int j = 0; j < 4; ++j) acc[j] = (f32x4)0.0f;

    // per-thread: 3 loads per step (2 A chunks + 1 B chunk)
    auto stage = [&](int buf, int kk) {
        h16* dst = smem + buf * 12288;
#pragma unroll
        for (int c = 0; c < 2; ++c) {
            int rb = w * 16 + c * 8;
            async_copy16(&dst[rb * 64], &A16[(size_t)(m0 + rb + sr) * DM + kk + scb * 8]);
        }
        async_copy16(&dst[8192 + (w * 8) * 64], &bw[(size_t)(n0 + w * 8 + sr) * DM + kk + scb * 8]);
    };

    // prologue: issue steps 0 and 1
    stage(0, 0);
    stage(1, 64);

    int step = 0;
    for (int k0 = 0; k0 < DM; k0 += 64, ++step) {
        const int buf = step - (step / 3) * 3;   // step % 3
        h16* As = smem + buf * 12288;
        h16* Bs = As + 8192;

        // outstanding: step k (3) + step k+1 (3) = 6 -> vmcnt(3) keeps k+1's
        // loads in flight across the barrier. Last step: vmcnt(0).
        __builtin_amdgcn_sched_barrier(0);
        if (k0 + 64 < DM) asm volatile("s_waitcnt vmcnt(3)" ::: "memory");
        else              asm volatile("s_waitcnt vmcnt(0)" ::: "memory");
        __builtin_amdgcn_s_barrier();
        __builtin_amdgcn_sched_barrier(0);

        if (k0 + 128 < DM) {
            int nb = step + 2;
            stage(nb - (nb / 3) * 3, k0 + 128);
        }

        __builtin_amdgcn_s_setprio(1);
#pragma unroll
        for (int ks = 0; ks < 2; ++ks) {
            half8 af, bf[4];
            af = *(const half8*)&As[(w * 16 + L) * 64 + SWZ(ks * 4 + U, L)];
#pragma unroll
            for (int nt = 0; nt < 4; ++nt)
                bf[nt] = *(const half8*)&Bs[(nt * 16 + L) * 64 + SWZ(ks * 4 + U, L)];
#pragma unroll
            for (int nt = 0; nt < 4; ++nt)
                acc[nt] = mfma16(af, bf[nt], acc[nt]);
        }
        __builtin_amdgcn_s_setprio(0);
    }

#pragma unroll
    for (int nt = 0; nt < 4; ++nt)
#pragma unroll
        for (int r = 0; r < 4; ++r) {
            int row = m0 + w * 16 + U * 4 + r;
            int col = n0 + nt * 16 + L;
            out[(size_t)row * DM + col] = acc[nt][r];
        }
}

extern "C" void kernel_launch(void* const* d_in, const int* in_sizes, int n_in,
                              void* d_out, int out_size, void* d_ws, size_t ws_size,
                              hipStream_t stream)
{
    const float* x    = (const float*)d_in[0];
    const float* fcos = (const float*)d_in[1];
    const float* fsin = (const float*)d_in[2];
    const float* wq   = (const float*)d_in[3];
    const float* wk   = (const float*)d_in[4];
    const float* wv   = (const float*)d_in[5];
    const float* wo   = (const float*)d_in[6];
    float* out = (float*)d_out;

    const size_t M4 = (size_t)4 * 1024 * 1024;
    h16* x16  = (h16*)d_ws;        // 4M halfs
    h16* wt   = x16 + M4;          // 4M (4 matrices, [n][k])
    h16* Q16  = wt + M4;           // 4M
    h16* K16  = Q16 + M4;          // 4M
    h16* VT16 = K16 + M4;          // 4M ([B,H,D,S])
    h16* A16  = VT16 + M4;         // 4M -> total 24M halfs = 48 MB

    prep_kernel<<<dim3(16, 16, 5), 256, 0, stream>>>(x, wq, wk, wv, wo, x16, wt);
    qkv_kernel<<<dim3(256), 512, 0, stream>>>(x16, wt, fcos, fsin,
                                              Q16, K16, VT16);
    attn_kernel<<<dim3(16, 32), 512, 0, stream>>>(Q16, K16, VT16, A16);
    oproj_kernel<<<dim3(16, 32), 512, 0, stream>>>(A16, wt + 3 * (size_t)DM * DM, out);
}